// Round 1
// baseline (165.023 us; speedup 1.0000x reference)
//
#include <hip/hip_runtime.h>
#include <math.h>

#define M_ 4
#define A_ 256
#define RBF_ 64
#define F_ 32
#define H_ 32
#define SI_ 32
#define TF_ 128   // 4 tags * F

typedef __attribute__((ext_vector_type(8))) short bf16x8;
typedef __attribute__((ext_vector_type(4))) float f32x4;
typedef __attribute__((ext_vector_type(3))) float f32x3;

__device__ __forceinline__ unsigned short f2bf(float f) {
  union { float f; unsigned u; } v; v.f = f;
  unsigned r = v.u + 0x7FFFu + ((v.u >> 16) & 1u);   // RNE bf16 (weights, one-time)
  return (unsigned short)(r >> 16);
}

// pack two fp32 -> two bf16 (round-half-up: +0x8000 then take hi16) in 3 VALU
__device__ __forceinline__ unsigned pack2bf(float lo, float hi) {
  union { float f; unsigned u; } a, b; a.f = lo; b.f = hi;
  return __builtin_amdgcn_perm(b.u + 0x8000u, a.u + 0x8000u, 0x07060302u);
}

__device__ __forceinline__ float sspf(float x) {
  // log(0.5*exp(x)+0.5) = softplus(x) - ln2, numerically stable
  return fmaxf(x, 0.f) + log1pf(expf(-fabsf(x))) - 0.6931471805599453f;
}

// ---------------------------------------------------------------------------
// Setup: collapse the two linear Dense layers per tag into one 64x32 map.
// ws layout: WcT bf16 [tf=128][k=64] (16384 B) | bc fp32[128] at +16384.
// tf = tag*32 + f, tag order {00,01,10,11}.
// ---------------------------------------------------------------------------
__global__ __launch_bounds__(256) void combine_weights(
    const float* __restrict__ w1_00, const float* __restrict__ b1_00,
    const float* __restrict__ w2_00, const float* __restrict__ b2_00,
    const float* __restrict__ w1_01, const float* __restrict__ b1_01,
    const float* __restrict__ w2_01, const float* __restrict__ b2_01,
    const float* __restrict__ w1_10, const float* __restrict__ b1_10,
    const float* __restrict__ w2_10, const float* __restrict__ b2_10,
    const float* __restrict__ w1_11, const float* __restrict__ b1_11,
    const float* __restrict__ w2_11, const float* __restrict__ b2_11,
    unsigned short* __restrict__ wsT, float* __restrict__ bcw)
{
  const float* w1s[4] = {w1_00, w1_01, w1_10, w1_11};
  const float* b1s[4] = {b1_00, b1_01, b1_10, b1_11};
  const float* w2s[4] = {w2_00, w2_01, w2_10, w2_11};
  const float* b2s[4] = {b2_00, b2_01, b2_10, b2_11};
  int tid = blockIdx.x * 256 + threadIdx.x;    // 0..8191
  int k   = tid >> 7;
  int tf  = tid & 127;
  int tag = tf >> 5, f = tf & 31;
  const float* w1 = w1s[tag];
  const float* w2 = w2s[tag];
  float s = 0.f;
  for (int h = 0; h < H_; ++h) s += w1[k * H_ + h] * w2[h * F_ + f];
  wsT[tf * 64 + k] = f2bf(s);                  // transposed for B-frag loads
  if (tid < TF_) {
    const float* b1 = b1s[tag];
    const float* b2 = b2s[tag];
    float sb = b2[f];
    for (int h = 0; h < H_; ++h) sb += b1[h] * w2[h * F_ + f];
    bcw[tf] = sb;                              // bias stays fp32
  }
}

// ---------------------------------------------------------------------------
// R12 FUSED kernel: one block per (m,a) -- grid 1024 (exactly 4 blocks/CU,
// single generation), 512 thr, 8 waves, wave-per-(tag,f-half) role as R8/R11.
//  Changes vs R11:
//   (1) Full 256-neighbor range per block; image streamed through a
//       2 x (32 rows x 64 rbf) double-buffered LDS ring (9.2 KB vs 18.4 KB).
//       Per chunk: all 512 threads load one float4, pack to bf16, ds_write.
//   (2) Raw s_barrier with lgkmcnt(0)-only drain (HK pattern) so next-chunk
//       image loads + feat prefetches stay in flight across barriers
//       (__syncthreads' vmcnt(0) drain was the exposed-latency killer).
//   (3) SI epilogue fused in-block: QRED partials -> LDS cat[352] ->
//       w_si dot + ssp/norm. Kills the part HBM round-trip (5.6 MB RW)
//       and the si_epilogue launch.
//  GEMM via mfma_f32_16x16x32_bf16; C-frag row(b)=quad*4+reg, col=lane&15.
//  LDS: sA 2x[32][72] bf16 (9216) + sV[768] f32 (3072) + cat[352] (1408)
//       = 13696 B.
//  Spill sentinel: WRITE_SIZE must stay ~0.55 MB (output only);
//  VGPR_Count must stay <= 64 (else 3 blocks/CU -> partial 2nd generation).
// ---------------------------------------------------------------------------
__global__ __launch_bounds__(512, 4) void conv_fused(
    const float* __restrict__ image, const float* __restrict__ vectors,
    const float* __restrict__ feat0, const float* __restrict__ feat1,
    const unsigned short* __restrict__ wsT, const float* __restrict__ bcw,
    const float* __restrict__ w_si0, const float* __restrict__ w_si1,
    const float* __restrict__ b_act0, const float* __restrict__ b_act1,
    float* __restrict__ out)
{
  __shared__ __align__(16) unsigned short sA[2][32 * 72];  // 9216 B
  __shared__ float sV[A_ * 3];                             // 3072 B
  __shared__ float cat[352];                               // 1408 B

  const int t    = threadIdx.x;
  const int ma   = blockIdx.x;      // m*256 + a
  const int m    = ma >> 8;
  const int l    = t & 63;
  const int n    = l & 15;
  const int quad = l >> 4;
  // wave id as SGPR -> uniform branches; rotate roles across SIMDs per block
  const int wu    = __builtin_amdgcn_readfirstlane(t >> 6);   // 0..7
  const int role  = (wu + ((ma & 3) << 1)) & 7;
  const int which = role & 1;
  const int tag   = role >> 1;      // 0:'00' 1:'01' 2:'10' 3:'11'
  const int ct    = tag * 2 + which;
  const int f     = which * 16 + n; // feature column this lane owns

  // ---- Wc fragment + bias into registers (global, L2-resident) ----
  const unsigned short* wr = wsT + (ct * 16 + n) * 64 + quad * 8;
  const bf16x8 w0 = *(const bf16x8*)(wr);
  const bf16x8 w1 = *(const bf16x8*)(wr + 32);
  const float  bc = bcw[ct * 16 + n];

  // ---- streaming stage addressing: thread t covers row t>>4, cols (t&15)*4
  const int srow = t >> 4;                 // 0..31
  const int scol = (t & 15) * 4;           // 0..60
  const float* gsrc = image + (size_t)ma * (A_ * RBF_) + srow * RBF_ + scol;
  unsigned short* sd0 = &sA[0][srow * 72 + scol];
  unsigned short* sd1 = &sA[1][srow * 72 + scol];

  // issue chunk0 + chunk1 image loads up front (latency under sV stage)
  float4 rE = *(const float4*)(gsrc);          // chunk 0
  float4 rO = *(const float4*)(gsrc + 2048);   // chunk 1
  gsrc += 4096;                                // -> chunk 2

  // ---- stage vectors (256 b x 3) to LDS ----
  {
    const float* vsrc = vectors + (size_t)ma * (A_ * 3);
    sV[t] = vsrc[t];
    if (t < 256) sV[t + 512] = vsrc[t + 512];
  }

  // ---- running feat pointers (advanced by constants; imm-offset loads) ----
  const int b0q = quad * 4;
  const float* p0c = feat0 + (size_t)(m * A_ + b0q) * F_ + f;       // feat0 col
  const float* p1c = feat1 + ((size_t)(m * A_ + b0q) * F_ + f) * 3; // feat1 col
  const float* svc = &sV[b0q * 3];
  const unsigned short* aB0 = &sA[0][n * 72 + quad * 8];
  const unsigned short* aB1 = &sA[1][n * 72 + quad * 8];

  float gx[2][4], gy[2][4], gz[2][4];
  float pA = 0.f, pB0 = 0.f, pB1 = 0.f, pB2 = 0.f;

#define PF(BUF) { \
    if (tag <= 1) { \
      _Pragma("unroll") \
      for (int r = 0; r < 4; ++r) gx[BUF][r] = p0c[r * F_]; \
    } else { \
      _Pragma("unroll") \
      for (int r = 0; r < 4; ++r) { \
        f32x3 v = *(const f32x3*)(p1c + r * (F_ * 3)); \
        gx[BUF][r] = v[0]; gy[BUF][r] = v[1]; gz[BUF][r] = v[2]; \
      } \
    } \
    p0c += 16 * F_; p1c += 16 * F_ * 3; }

#define BODY(AB, AOFF, SOFF, GX, GY, GZ) { \
    const bf16x8 a0 = *(const bf16x8*)(AB + (AOFF)); \
    const bf16x8 a1 = *(const bf16x8*)(AB + (AOFF) + 32); \
    f32x4 acc = {bc, bc, bc, bc}; \
    acc = __builtin_amdgcn_mfma_f32_16x16x32_bf16(a0, w0, acc, 0, 0, 0); \
    acc = __builtin_amdgcn_mfma_f32_16x16x32_bf16(a1, w1, acc, 0, 0, 0); \
    if (tag == 0) {            /* out_0x0_0 */ \
      _Pragma("unroll") \
      for (int r = 0; r < 4; ++r) pA += acc[r] * GX[r]; \
    } else if (tag == 1) {     /* out_0x1_1 = v * (R*feat0) */ \
      _Pragma("unroll") \
      for (int r = 0; r < 4; ++r) { \
        const float s = acc[r] * GX[r]; \
        pB0 += svc[(SOFF) + r * 3 + 0] * s; \
        pB1 += svc[(SOFF) + r * 3 + 1] * s; \
        pB2 += svc[(SOFF) + r * 3 + 2] * s; \
      } \
    } else if (tag == 2) {     /* out_1x0_1 = R * feat1 */ \
      _Pragma("unroll") \
      for (int r = 0; r < 4; ++r) { \
        const float Rr = acc[r]; \
        pB0 += Rr * GX[r]; pB1 += Rr * GY[r]; pB2 += Rr * GZ[r]; \
      } \
    } else {                   /* out_1x1_0 (dot) + out_1x1_1 (cross) */ \
      _Pragma("unroll") \
      for (int r = 0; r < 4; ++r) { \
        const float Rr = acc[r]; \
        const float ax = GX[r], ay = GY[r], az = GZ[r]; \
        const float vx = svc[(SOFF) + r * 3 + 0]; \
        const float vy = svc[(SOFF) + r * 3 + 1]; \
        const float vz = svc[(SOFF) + r * 3 + 2]; \
        float d = vx * ax; d = fmaf(vy, ay, d); d = fmaf(vz, az, d); \
        pA = fmaf(Rr, d, pA); \
        float c0 = vy * az; c0 = fmaf(-vz, ay, c0); pB0 = fmaf(Rr, c0, pB0); \
        float c1 = vz * ax; c1 = fmaf(-vx, az, c1); pB1 = fmaf(Rr, c1, pB1); \
        float c2 = vx * ay; c2 = fmaf(-vy, ax, c2); pB2 = fmaf(Rr, c2, pB2); \
      } \
    } }

  // lgkmcnt-only barrier: ds ops drained, global loads STAY IN FLIGHT.
  // asm memory clobbers fence the compiler on both sides (guide S5 pattern).
#define BARRIER() { \
    asm volatile("s_waitcnt lgkmcnt(0)" ::: "memory"); \
    __builtin_amdgcn_s_barrier(); \
    asm volatile("" ::: "memory"); }

  PF(0)                                 // feat tile 0 (in flight over barrier)
  { uint2 pk; pk.x = pack2bf(rE.x, rE.y); pk.y = pack2bf(rE.z, rE.w);
    *(uint2*)sd0 = pk; }                // write chunk 0 (waits rE only; rO flies)
  BARRIER();

  // 8 chunks of 32 rows = 16 b-tiles; 2 bodies/chunk; 1 barrier/chunk.
  #pragma unroll 1
  for (int d = 0; d < 4; ++d) {
    // ---- even chunk c=2d (buffer 0): tiles 4d, 4d+1 ----
    if (d < 3) rE = *(const float4*)(gsrc);             // load chunk 2d+2
    PF(1)                                               // feat tile 4d+1
    BODY(aB0, 0, 0, gx[0], gy[0], gz[0])                // tile 4d
    PF(0)                                               // feat tile 4d+2 (<=14)
    BODY(aB0, 1152, 48, gx[1], gy[1], gz[1])            // tile 4d+1
    { uint2 pk; pk.x = pack2bf(rO.x, rO.y); pk.y = pack2bf(rO.z, rO.w);
      *(uint2*)sd1 = pk; }                              // write chunk 2d+1
    BARRIER();
    // ---- odd chunk c=2d+1 (buffer 1): tiles 4d+2, 4d+3 ----
    if (d < 3) rO = *(const float4*)(gsrc + 2048);      // load chunk 2d+3
    PF(1)                                               // feat tile 4d+3
    BODY(aB1, 0, 96, gx[0], gy[0], gz[0])               // tile 4d+2
    if (d < 3) PF(0)                                    // feat tile 4d+4
    BODY(aB1, 1152, 144, gx[1], gy[1], gz[1])           // tile 4d+3
    if (d < 3) {
      uint2 pk; pk.x = pack2bf(rE.x, rE.y); pk.y = pack2bf(rE.z, rE.w);
      *(uint2*)sd0 = pk;                                // write chunk 2d+2
      BARRIER();
    }
    gsrc += 4096;
    svc  += 192;
  }

  // ---- reduce the 4 quad-copies, partials to LDS cat[] ----
#define QRED(x) { x += __shfl_xor(x, 16); x += __shfl_xor(x, 32); }
  QRED(pA) QRED(pB0) QRED(pB1) QRED(pB2)
  if (quad == 0) {
    // slots (cat order): out000: f | out110: 32+f | out011: 64+f*3+d
    //                    out101: 160+f*3+d | out111: 256+f*3+d
    if (tag == 0) {
      cat[f] = pA;
    } else if (tag == 1) {
      cat[64 + f * 3 + 0] = pB0; cat[64 + f * 3 + 1] = pB1; cat[64 + f * 3 + 2] = pB2;
    } else if (tag == 2) {
      cat[160 + f * 3 + 0] = pB0; cat[160 + f * 3 + 1] = pB1; cat[160 + f * 3 + 2] = pB2;
    } else {
      cat[32 + f] = pA;
      cat[256 + f * 3 + 0] = pB0; cat[256 + f * 3 + 1] = pB1; cat[256 + f * 3 + 2] = pB2;
    }
  }
  __syncthreads();   // full drain once; epilogue reads cat

  // ---- fused self-interaction + equivariant activation ----
  if (t < 256) {
    // SI1: 32 outputs x 3 comps; 8 lanes per output, 12 ff-terms each
    const int g = t >> 3, p = t & 7;
    const float* wrow = w_si1 + g * 96 + p * 12;
    const float* c1 = &cat[64 + p * 36];
    float s0 = 0.f, s1 = 0.f, s2 = 0.f;
    #pragma unroll
    for (int k = 0; k < 12; ++k) {
      const float wv = wrow[k];
      s0 = fmaf(c1[k * 3 + 0], wv, s0);
      s1 = fmaf(c1[k * 3 + 1], wv, s1);
      s2 = fmaf(c1[k * 3 + 2], wv, s2);
    }
    s0 += __shfl_xor(s0, 1); s0 += __shfl_xor(s0, 2); s0 += __shfl_xor(s0, 4);
    s1 += __shfl_xor(s1, 1); s1 += __shfl_xor(s1, 2); s1 += __shfl_xor(s1, 4);
    s2 += __shfl_xor(s2, 1); s2 += __shfl_xor(s2, 2); s2 += __shfl_xor(s2, 4);
    if (p == 0) {
      const float n2 = s0 * s0 + s1 * s1 + s2 * s2;
      const float n1 = sqrtf(fmaxf(n2, 1e-7f));     // norm_with_epsilon
      const float a1 = sspf(n1 + b_act1[g]);
      const float sc = a1 / n1;
      const int ob = M_ * A_ * SI_ + (ma * SI_ + g) * 3;
      out[ob + 0] = s0 * sc; out[ob + 1] = s1 * sc; out[ob + 2] = s2 * sc;
    }
  } else if (t < 320) {
    // SI0: 32 outputs; 2 lanes per output, 32 ff-terms each (wave 4 only)
    const int t2 = t - 256, g = t2 >> 1, p = t2 & 1;
    const float* wrow = w_si0 + g * 64 + p * 32;
    const float* c0 = &cat[p * 32];
    float s = 0.f;
    #pragma unroll 8
    for (int k = 0; k < 32; ++k) s = fmaf(c0[k], wrow[k], s);
    s += __shfl_xor(s, 1);
    if (p == 0) out[ma * SI_ + g] = sspf(s + b_act0[g]);
  }
}

extern "C" void kernel_launch(void* const* d_in, const int* in_sizes, int n_in,
                              void* d_out, int out_size, void* d_ws, size_t ws_size,
                              hipStream_t stream) {
  const float* image   = (const float*)d_in[0];
  const float* vectors = (const float*)d_in[1];
  const float* feat0   = (const float*)d_in[2];
  const float* feat1   = (const float*)d_in[3];
  const float* w_si0   = (const float*)d_in[20];
  const float* w_si1   = (const float*)d_in[21];
  const float* b_act0  = (const float*)d_in[22];
  const float* b_act1  = (const float*)d_in[23];
  unsigned short* wsT = (unsigned short*)d_ws;           // 128*64 bf16 = 16384 B
  float* bcw  = (float*)((char*)d_ws + 16384);           // 128 f32
  float* out  = (float*)d_out;

  combine_weights<<<32, 256, 0, stream>>>(
      (const float*)d_in[4],  (const float*)d_in[5],
      (const float*)d_in[6],  (const float*)d_in[7],
      (const float*)d_in[8],  (const float*)d_in[9],
      (const float*)d_in[10], (const float*)d_in[11],
      (const float*)d_in[12], (const float*)d_in[13],
      (const float*)d_in[14], (const float*)d_in[15],
      (const float*)d_in[16], (const float*)d_in[17],
      (const float*)d_in[18], (const float*)d_in[19],
      wsT, bcw);

  conv_fused<<<M_ * A_, 512, 0, stream>>>(
      image, vectors, feat0, feat1, wsT, bcw,
      w_si0, w_si1, b_act0, b_act1, out);
}

// Round 2
// 158.821 us; speedup vs baseline: 1.0390x; 1.0390x over previous
//
#include <hip/hip_runtime.h>
#include <math.h>

#define M_ 4
#define A_ 256
#define RBF_ 64
#define F_ 32
#define H_ 32
#define SI_ 32
#define TF_ 128   // 4 tags * F

typedef __attribute__((ext_vector_type(8))) short bf16x8;
typedef __attribute__((ext_vector_type(4))) float f32x4;
typedef __attribute__((ext_vector_type(3))) float f32x3;

__device__ __forceinline__ unsigned short f2bf(float f) {
  union { float f; unsigned u; } v; v.f = f;
  unsigned r = v.u + 0x7FFFu + ((v.u >> 16) & 1u);   // RNE bf16 (weights, one-time)
  return (unsigned short)(r >> 16);
}

// pack two fp32 -> two bf16 (round-half-up: +0x8000 then take hi16) in 3 VALU
__device__ __forceinline__ unsigned pack2bf(float lo, float hi) {
  union { float f; unsigned u; } a, b; a.f = lo; b.f = hi;
  return __builtin_amdgcn_perm(b.u + 0x8000u, a.u + 0x8000u, 0x07060302u);
}

__device__ __forceinline__ float sspf(float x) {
  // log(0.5*exp(x)+0.5) = softplus(x) - ln2, numerically stable
  return fmaxf(x, 0.f) + log1pf(expf(-fabsf(x))) - 0.6931471805599453f;
}

// ---------------------------------------------------------------------------
// Setup: collapse the two linear Dense layers per tag into one 64x32 map.
// ws layout: WcT bf16 [tf=128][k=64] (16384 B) | bc fp32[128] at +16384.
// tf = tag*32 + f, tag order {00,01,10,11}.
// ---------------------------------------------------------------------------
__global__ __launch_bounds__(256) void combine_weights(
    const float* __restrict__ w1_00, const float* __restrict__ b1_00,
    const float* __restrict__ w2_00, const float* __restrict__ b2_00,
    const float* __restrict__ w1_01, const float* __restrict__ b1_01,
    const float* __restrict__ w2_01, const float* __restrict__ b2_01,
    const float* __restrict__ w1_10, const float* __restrict__ b1_10,
    const float* __restrict__ w2_10, const float* __restrict__ b2_10,
    const float* __restrict__ w1_11, const float* __restrict__ b1_11,
    const float* __restrict__ w2_11, const float* __restrict__ b2_11,
    unsigned short* __restrict__ wsT, float* __restrict__ bcw)
{
  const float* w1s[4] = {w1_00, w1_01, w1_10, w1_11};
  const float* b1s[4] = {b1_00, b1_01, b1_10, b1_11};
  const float* w2s[4] = {w2_00, w2_01, w2_10, w2_11};
  const float* b2s[4] = {b2_00, b2_01, b2_10, b2_11};
  int tid = blockIdx.x * 256 + threadIdx.x;    // 0..8191
  int k   = tid >> 7;
  int tf  = tid & 127;
  int tag = tf >> 5, f = tf & 31;
  const float* w1 = w1s[tag];
  const float* w2 = w2s[tag];
  float s = 0.f;
  for (int h = 0; h < H_; ++h) s += w1[k * H_ + h] * w2[h * F_ + f];
  wsT[tf * 64 + k] = f2bf(s);                  // transposed for B-frag loads
  if (tid < TF_) {
    const float* b1 = b1s[tag];
    const float* b2 = b2s[tag];
    float sb = b2[f];
    for (int h = 0; h < H_; ++h) sb += b1[h] * w2[h * F_ + f];
    bcw[tf] = sb;                              // bias stays fp32
  }
}

// ---------------------------------------------------------------------------
// R13 FUSED kernel: one block per (m,a) -- grid 1024 (4 blocks/CU, single
// generation), 512 thr, 8 waves, wave-per-(tag,f-half) role as R8/R11.
//  Post-mortem of R12 (45-47us, VALUBusy 28%): the 8-barrier chunk ring was
//  the regression -- R0's {stage, ONE barrier, free-run} shape overlapped
//  better (41us). R12 also leaked ~5.8 MB of stray writes (scratch).
//  R13 = R0's shape at full 256-row depth + fused epilogue:
//   - sA [256][72] bf16 (36864 B), single buffer, stride 72 (16B-aligned
//     rows, 2-way-free bank aliasing, proven in R8).
//   - H1 (rows 0..127) staged in prologue: 4 float4/thread, pack, 2x b128
//     ds_write. Exposed ~5us (BW-bound burst, unavoidable first touch).
//   - H2 (rows 128..255) streamed with ONE float4 in flight per thread,
//     issued/packed at 2-tile intervals inside the tiles-0..7 run ->
//     H2's HBM latency+BW hides under compute, no barrier chain, no
//     VGPR blowup (R12's rE/rO+gx pressure -> scratch).
//   - 2 lgkm-only barriers total; tiles 8..15 run with zero syncs.
//   - cat[] overlaid on sV (union) -> LDS 39936 B/block, 4 blocks/CU.
//  GEMM via mfma_f32_16x16x32_bf16; C-frag row(b)=quad*4+reg, col=lane&15.
//  Spill sentinel: WRITE_SIZE must be ~0.5-1 MB (output only);
//  VGPR_Count must stay <= 64 (else occupancy halves).
// ---------------------------------------------------------------------------
__global__ __launch_bounds__(512, 4) void conv_fused(
    const float* __restrict__ image, const float* __restrict__ vectors,
    const float* __restrict__ feat0, const float* __restrict__ feat1,
    const unsigned short* __restrict__ wsT, const float* __restrict__ bcw,
    const float* __restrict__ w_si0, const float* __restrict__ w_si1,
    const float* __restrict__ b_act0, const float* __restrict__ b_act1,
    float* __restrict__ out)
{
  __shared__ __align__(16) unsigned short sA[256 * 72];    // 36864 B
  __shared__ __align__(16) float sV[A_ * 3];               // 3072 B (cat overlays)
  float* const cat = sV;                                   // reused after sync

  const int t    = threadIdx.x;
  const int ma   = blockIdx.x;      // m*256 + a
  const int m    = ma >> 8;
  const int l    = t & 63;
  const int n    = l & 15;
  const int quad = l >> 4;
  // wave id as SGPR -> uniform branches; rotate roles across SIMDs per block
  const int wu    = __builtin_amdgcn_readfirstlane(t >> 6);   // 0..7
  const int role  = (wu + ((ma & 3) << 1)) & 7;
  const int which = role & 1;
  const int tag   = role >> 1;      // 0:'00' 1:'01' 2:'10' 3:'11'
  const int ct    = tag * 2 + which;
  const int f     = which * 16 + n; // feature column this lane owns

  // ---- Wc fragment + bias into registers (global, L2-resident) ----
  const unsigned short* wr = wsT + (ct * 16 + n) * 64 + quad * 8;
  const bf16x8 w0 = *(const bf16x8*)(wr);
  const bf16x8 w1 = *(const bf16x8*)(wr + 32);
  const float  bc = bcw[ct * 16 + n];

  // ---- stage addressing: thread t owns row t>>2 (0..127), cols (t&3)*16 ----
  const int srow = t >> 2;
  const int sc16 = (t & 3) << 4;
  const float* g1 = image + (size_t)ma * (A_ * RBF_) + srow * RBF_ + sc16;
  const float* g2 = g1 + 128 * RBF_;                 // H2 source (rows +128)
  unsigned short* w1p = &sA[srow * 72 + sc16];
  unsigned short* w2p = &sA[(srow + 128) * 72 + sc16];

  // ---- H1: 4 float4 loads, pack, two b128 LDS writes ----
  float4 a0 = *(const float4*)(g1);
  float4 a1 = *(const float4*)(g1 + 4);
  float4 a2 = *(const float4*)(g1 + 8);
  float4 a3 = *(const float4*)(g1 + 12);
  // ---- stage vectors (256 b x 3) to LDS ----
  {
    const float* vsrc = vectors + (size_t)ma * (A_ * 3);
    sV[t] = vsrc[t];
    if (t < 256) sV[t + 512] = vsrc[t + 512];
  }
  {
    uint4 pk;
    pk.x = pack2bf(a0.x, a0.y); pk.y = pack2bf(a0.z, a0.w);
    pk.z = pack2bf(a1.x, a1.y); pk.w = pack2bf(a1.z, a1.w);
    *(uint4*)w1p = pk;
    pk.x = pack2bf(a2.x, a2.y); pk.y = pack2bf(a2.z, a2.w);
    pk.z = pack2bf(a3.x, a3.y); pk.w = pack2bf(a3.z, a3.w);
    *(uint4*)(w1p + 8) = pk;
  }
  // first H2 quarter in flight across the barrier
  float4 hb = *(const float4*)(g2);

  // ---- running feat pointers (advanced by constants; imm-offset loads) ----
  const int b0q = quad * 4;
  const float* p0c = feat0 + (size_t)(m * A_ + b0q) * F_ + f;       // feat0 col
  const float* p1c = feat1 + ((size_t)(m * A_ + b0q) * F_ + f) * 3; // feat1 col
  const float* svc = &sV[b0q * 3];
  const unsigned short* aBc = &sA[n * 72 + quad * 8];

  float gx[2][4], gy[2][4], gz[2][4];
  float pA = 0.f, pB0 = 0.f, pB1 = 0.f, pB2 = 0.f;

#define PF(BUF) { \
    if (tag <= 1) { \
      _Pragma("unroll") \
      for (int r = 0; r < 4; ++r) gx[BUF][r] = p0c[r * F_]; \
    } else { \
      _Pragma("unroll") \
      for (int r = 0; r < 4; ++r) { \
        f32x3 v = *(const f32x3*)(p1c + r * (F_ * 3)); \
        gx[BUF][r] = v[0]; gy[BUF][r] = v[1]; gz[BUF][r] = v[2]; \
      } \
    } \
    p0c += 16 * F_; p1c += 16 * F_ * 3; }

#define BODY(AOFF, SOFF, GX, GY, GZ) { \
    const bf16x8 a0_ = *(const bf16x8*)(aBc + (AOFF)); \
    const bf16x8 a1_ = *(const bf16x8*)(aBc + (AOFF) + 32); \
    f32x4 acc = {bc, bc, bc, bc}; \
    acc = __builtin_amdgcn_mfma_f32_16x16x32_bf16(a0_, w0, acc, 0, 0, 0); \
    acc = __builtin_amdgcn_mfma_f32_16x16x32_bf16(a1_, w1, acc, 0, 0, 0); \
    if (tag == 0) {            /* out_0x0_0 */ \
      _Pragma("unroll") \
      for (int r = 0; r < 4; ++r) pA += acc[r] * GX[r]; \
    } else if (tag == 1) {     /* out_0x1_1 = v * (R*feat0) */ \
      _Pragma("unroll") \
      for (int r = 0; r < 4; ++r) { \
        const float s = acc[r] * GX[r]; \
        pB0 += svc[(SOFF) + r * 3 + 0] * s; \
        pB1 += svc[(SOFF) + r * 3 + 1] * s; \
        pB2 += svc[(SOFF) + r * 3 + 2] * s; \
      } \
    } else if (tag == 2) {     /* out_1x0_1 = R * feat1 */ \
      _Pragma("unroll") \
      for (int r = 0; r < 4; ++r) { \
        const float Rr = acc[r]; \
        pB0 += Rr * GX[r]; pB1 += Rr * GY[r]; pB2 += Rr * GZ[r]; \
      } \
    } else {                   /* out_1x1_0 (dot) + out_1x1_1 (cross) */ \
      _Pragma("unroll") \
      for (int r = 0; r < 4; ++r) { \
        const float Rr = acc[r]; \
        const float ax = GX[r], ay = GY[r], az = GZ[r]; \
        const float vx = svc[(SOFF) + r * 3 + 0]; \
        const float vy = svc[(SOFF) + r * 3 + 1]; \
        const float vz = svc[(SOFF) + r * 3 + 2]; \
        float d = vx * ax; d = fmaf(vy, ay, d); d = fmaf(vz, az, d); \
        pA = fmaf(Rr, d, pA); \
        float c0 = vy * az; c0 = fmaf(-vz, ay, c0); pB0 = fmaf(Rr, c0, pB0); \
        float c1 = vz * ax; c1 = fmaf(-vx, az, c1); pB1 = fmaf(Rr, c1, pB1); \
        float c2 = vx * ay; c2 = fmaf(-vy, ax, c2); pB2 = fmaf(Rr, c2, pB2); \
      } \
    } }

  // lgkm-only barrier: ds ops drained, global loads STAY IN FLIGHT.
#define BARRIER() { \
    asm volatile("s_waitcnt lgkmcnt(0)" ::: "memory"); \
    __builtin_amdgcn_s_barrier(); \
    asm volatile("" ::: "memory"); }

  PF(0)                                 // feat tile 0 (in flight over barrier)
  BARRIER();

  // ---- tiles 0..7 (H1 rows), H2 stream interleaved: 1 f4 in flight ----
  #pragma unroll 1
  for (int d = 0; d < 4; ++d) {
    PF(1)                                               // feat tile 2d+1
    BODY(0, 0, gx[0], gy[0], gz[0])                     // tile 2d
    PF(0)                                               // feat tile 2d+2
    BODY(1152, 48, gx[1], gy[1], gz[1])                 // tile 2d+1
    aBc += 2304; svc += 96;
    // pack the in-flight H2 quarter (vmcnt waits hb; ~2 tiles of lead)
    { uint2 pk; pk.x = pack2bf(hb.x, hb.y); pk.y = pack2bf(hb.z, hb.w);
      *(uint2*)w2p = pk; }
    w2p += 4;
    if (d < 3) { g2 += 4; hb = *(const float4*)(g2); }  // issue next quarter
  }
  BARRIER();                            // H2 ds_writes drained; rows 128+ ready

  // ---- tiles 8..15: straight-line, zero syncs ----
  #pragma unroll 1
  for (int d = 0; d < 4; ++d) {
    PF(1)                                               // feat tile 2d+9
    BODY(0, 0, gx[0], gy[0], gz[0])                     // tile 2d+8
    if (d < 3) PF(0)                                    // feat tile 2d+10
    BODY(1152, 48, gx[1], gy[1], gz[1])                 // tile 2d+9
    aBc += 2304; svc += 96;
  }

  // ---- reduce the 4 quad-copies ----
#define QRED(x) { x += __shfl_xor(x, 16); x += __shfl_xor(x, 32); }
  QRED(pA) QRED(pB0) QRED(pB1) QRED(pB2)
  __syncthreads();            // all sV reads done (cat overlays sV)
  if (quad == 0) {
    // slots (cat order): out000: f | out110: 32+f | out011: 64+f*3+d
    //                    out101: 160+f*3+d | out111: 256+f*3+d
    if (tag == 0) {
      cat[f] = pA;
    } else if (tag == 1) {
      cat[64 + f * 3 + 0] = pB0; cat[64 + f * 3 + 1] = pB1; cat[64 + f * 3 + 2] = pB2;
    } else if (tag == 2) {
      cat[160 + f * 3 + 0] = pB0; cat[160 + f * 3 + 1] = pB1; cat[160 + f * 3 + 2] = pB2;
    } else {
      cat[32 + f] = pA;
      cat[256 + f * 3 + 0] = pB0; cat[256 + f * 3 + 1] = pB1; cat[256 + f * 3 + 2] = pB2;
    }
  }
  __syncthreads();            // cat visible to all

  // ---- fused self-interaction + equivariant activation ----
  if (t < 256) {
    // SI1: 32 outputs x 3 comps; 8 lanes per output, 12 ff-terms each
    const int g = t >> 3, p = t & 7;
    const float* wrow = w_si1 + g * 96 + p * 12;
    const float* c1 = &cat[64 + p * 36];
    float s0 = 0.f, s1 = 0.f, s2 = 0.f;
    #pragma unroll
    for (int k = 0; k < 12; ++k) {
      const float wv = wrow[k];
      s0 = fmaf(c1[k * 3 + 0], wv, s0);
      s1 = fmaf(c1[k * 3 + 1], wv, s1);
      s2 = fmaf(c1[k * 3 + 2], wv, s2);
    }
    s0 += __shfl_xor(s0, 1); s0 += __shfl_xor(s0, 2); s0 += __shfl_xor(s0, 4);
    s1 += __shfl_xor(s1, 1); s1 += __shfl_xor(s1, 2); s1 += __shfl_xor(s1, 4);
    s2 += __shfl_xor(s2, 1); s2 += __shfl_xor(s2, 2); s2 += __shfl_xor(s2, 4);
    if (p == 0) {
      const float n2 = s0 * s0 + s1 * s1 + s2 * s2;
      const float n1 = sqrtf(fmaxf(n2, 1e-7f));     // norm_with_epsilon
      const float a1 = sspf(n1 + b_act1[g]);
      const float sc = a1 / n1;
      const int ob = M_ * A_ * SI_ + (ma * SI_ + g) * 3;
      out[ob + 0] = s0 * sc; out[ob + 1] = s1 * sc; out[ob + 2] = s2 * sc;
    }
  } else if (t < 320) {
    // SI0: 32 outputs; 2 lanes per output, 32 ff-terms each (wave 4 only)
    const int t2 = t - 256, g = t2 >> 1, p = t2 & 1;
    const float* wrow = w_si0 + g * 64 + p * 32;
    const float* c0 = &cat[p * 32];
    float s = 0.f;
    #pragma unroll 8
    for (int k = 0; k < 32; ++k) s = fmaf(c0[k], wrow[k], s);
    s += __shfl_xor(s, 1);
    if (p == 0) out[ma * SI_ + g] = sspf(s + b_act0[g]);
  }
}

extern "C" void kernel_launch(void* const* d_in, const int* in_sizes, int n_in,
                              void* d_out, int out_size, void* d_ws, size_t ws_size,
                              hipStream_t stream) {
  const float* image   = (const float*)d_in[0];
  const float* vectors = (const float*)d_in[1];
  const float* feat0   = (const float*)d_in[2];
  const float* feat1   = (const float*)d_in[3];
  const float* w_si0   = (const float*)d_in[20];
  const float* w_si1   = (const float*)d_in[21];
  const float* b_act0  = (const float*)d_in[22];
  const float* b_act1  = (const float*)d_in[23];
  unsigned short* wsT = (unsigned short*)d_ws;           // 128*64 bf16 = 16384 B
  float* bcw  = (float*)((char*)d_ws + 16384);           // 128 f32
  float* out  = (float*)d_out;

  combine_weights<<<32, 256, 0, stream>>>(
      (const float*)d_in[4],  (const float*)d_in[5],
      (const float*)d_in[6],  (const float*)d_in[7],
      (const float*)d_in[8],  (const float*)d_in[9],
      (const float*)d_in[10], (const float*)d_in[11],
      (const float*)d_in[12], (const float*)d_in[13],
      (const float*)d_in[14], (const float*)d_in[15],
      (const float*)d_in[16], (const float*)d_in[17],
      (const float*)d_in[18], (const float*)d_in[19],
      wsT, bcw);

  conv_fused<<<M_ * A_, 512, 0, stream>>>(
      image, vectors, feat0, feat1, wsT, bcw,
      w_si0, w_si1, b_act0, b_act1, out);
}